// Round 2
// baseline (44.080 us; speedup 1.0000x reference)
//
#include <hip/hip_runtime.h>
#include <hip/hip_cooperative_groups.h>

namespace cg = cooperative_groups;

#define GAMMA 0.99f
#define TAU   0.95f

constexpr int SEQ   = 16;          // elements per thread
constexpr int BLK   = 256;         // threads per block
constexpr int CHUNK = BLK * SEQ;   // 4096 elements per block

// (A,B) = (A,B) ∘ (rA,rB)  — apply right operand first, then (A,B)
__device__ __forceinline__ void post_compose(float& A, float& B, float rA, float rB) {
    B = fmaf(A, rB, B);
    A *= rA;
}
// (A,B) = (lA,lB) ∘ (A,B)  — apply (A,B) first, then left operand
__device__ __forceinline__ void pre_compose(float& A, float& B, float lA, float lB) {
    B = fmaf(lA, B, lB);
    A *= lA;
}

// =====================================================================
// Fused single-pass cooperative kernel.
//   Phase A: load chunk once (registers), per-block affine summary -> ws
//   grid.sync()
//   Phase B: every block redundantly suffix-scans the <=1024 summaries
//            (16KB, L2/L3 resident) and extracts its own carry
//   Phase C: replay from registers, float4 stores
// Requires gridDim.x == ceil(T/CHUNK) <= 1024 and co-residency (checked
// host-side via occupancy query; falls back to 3-kernel path otherwise).
// =====================================================================
__global__ __launch_bounds__(BLK, 4) void k_fused(
    const float* __restrict__ r, const float* __restrict__ v,
    const float* __restrict__ nv, const int* __restrict__ m,
    float4* __restrict__ blk_sum,
    float* __restrict__ out_adv, float* __restrict__ out_ret, int T)
{
    const int  tid  = threadIdx.x;
    const int  lane = tid & 63;
    const int  w    = tid >> 6;
    const int  b    = blockIdx.x;
    const int  nblk = gridDim.x;
    const long base = (long)b * CHUNK + (long)tid * SEQ;

    float fm[SEQ], delta[SEQ], dd[SEQ];
    unsigned vbits = 0;
    float Aa = 1.f, Ba = 0.f, Ar = 1.f, Br = 0.f;
    const bool full = (base + SEQ <= (long)T);

    // ---------------- Phase A: load + per-element maps ----------------
    if (full) {
        vbits = 0xFFFFu;
        float rr[SEQ], vv[SEQ + 1], nn[SEQ];
        #pragma unroll
        for (int q = 0; q < SEQ / 4; ++q) {
            float4 t0 = ((const float4*)(r  + base))[q];
            rr[4*q+0]=t0.x; rr[4*q+1]=t0.y; rr[4*q+2]=t0.z; rr[4*q+3]=t0.w;
            float4 t1 = ((const float4*)(v  + base))[q];
            vv[4*q+0]=t1.x; vv[4*q+1]=t1.y; vv[4*q+2]=t1.z; vv[4*q+3]=t1.w;
            float4 t2 = ((const float4*)(nv + base))[q];
            nn[4*q+0]=t2.x; nn[4*q+1]=t2.y; nn[4*q+2]=t2.z; nn[4*q+3]=t2.w;
            int4   t3 = ((const int4*)(m   + base))[q];
            fm[4*q+0]=(float)t3.x; fm[4*q+1]=(float)t3.y;
            fm[4*q+2]=(float)t3.z; fm[4*q+3]=(float)t3.w;
        }
        vv[SEQ] = (base + SEQ < (long)T) ? v[base + SEQ] : 0.f;
        #pragma unroll
        for (int i = SEQ - 1; i >= 0; --i) {
            delta[i] = rr[i] + GAMMA * fm[i] * vv[i+1] - vv[i];
            dd[i]    = rr[i] + GAMMA * (1.f - fm[i]) * nn[i];
            pre_compose(Aa, Ba, GAMMA * TAU * fm[i], delta[i]);
            pre_compose(Ar, Br, GAMMA * fm[i], dd[i]);
        }
    } else {
        #pragma unroll
        for (int ii = 0; ii < SEQ; ++ii) {
            int i = SEQ - 1 - ii;
            long idx = base + i;
            bool val = idx < (long)T;
            float rr  = val ? r[idx]  : 0.f;
            float vv0 = val ? v[idx]  : 0.f;
            float vv1 = (idx + 1 < (long)T) ? v[idx + 1] : 0.f;
            float nn  = val ? nv[idx] : 0.f;
            fm[i] = val ? (float)m[idx] : 0.f;
            if (val) vbits |= (1u << i);
            delta[i] = val ? (rr + GAMMA * fm[i] * vv1 - vv0) : 0.f;
            dd[i]    = val ? (rr + GAMMA * (1.f - fm[i]) * nn) : 0.f;
            pre_compose(Aa, Ba, val ? GAMMA * TAU * fm[i] : 1.f, delta[i]);
            pre_compose(Ar, Br, val ? GAMMA * fm[i] : 1.f, dd[i]);
        }
    }

    // wave-level inclusive suffix scan (contiguous segments -> OK non-commutative)
    #pragma unroll
    for (int st = 1; st < 64; st <<= 1) {
        float oAa = __shfl_down(Aa, st);
        float oBa = __shfl_down(Ba, st);
        float oAr = __shfl_down(Ar, st);
        float oBr = __shfl_down(Br, st);
        if (lane + st < 64) {
            post_compose(Aa, Ba, oAa, oBa);
            post_compose(Ar, Br, oAr, oBr);
        }
    }
    // thread-exclusive (within wave)
    float eAa = __shfl_down(Aa, 1);
    float eBa = __shfl_down(Ba, 1);
    float eAr = __shfl_down(Ar, 1);
    float eBr = __shfl_down(Br, 1);
    if (lane == 63) { eAa=1.f; eBa=0.f; eAr=1.f; eBr=0.f; }

    __shared__ float wSum[4][4];
    __shared__ float s_cb[2];
    if (lane == 0) { wSum[w][0]=Aa; wSum[w][1]=Ba; wSum[w][2]=Ar; wSum[w][3]=Br; }
    __syncthreads();

    // wave-exclusive map (waves w+1..3) — keep in registers across grid sync
    float WAa=1.f, WBa=0.f, WAr=1.f, WBr=0.f;
    for (int j = 3; j > w; --j) {
        pre_compose(WAa, WBa, wSum[j][0], wSum[j][1]);
        pre_compose(WAr, WBr, wSum[j][2], wSum[j][3]);
    }

    // block summary -> workspace
    if (tid == 0) {
        float SAa=1.f, SBa=0.f, SAr=1.f, SBr=0.f;
        for (int j = 3; j >= 0; --j) {
            pre_compose(SAa, SBa, wSum[j][0], wSum[j][1]);
            pre_compose(SAr, SBr, wSum[j][2], wSum[j][3]);
        }
        blk_sum[b] = make_float4(SAa, SBa, SAr, SBr);
    }

    __threadfence();            // release: push blk_sum past XCD L2
    cg::this_grid().sync();
    __threadfence();            // acquire: invalidate stale cached lines

    // ---------------- Phase B: redundant suffix scan of block summaries ----------------
    // thread t owns summary indices 4t .. 4t+3 (covers up to 1024 blocks)
    const int p = b + 1;        // position whose value is this block's carry
    float sA[4][4];
    float gAa=1.f, gBa=0.f, gAr=1.f, gBr=0.f;
    #pragma unroll
    for (int j = 3; j >= 0; --j) {
        int idx = 4 * tid + j;
        float4 s = (idx < nblk) ? blk_sum[idx] : make_float4(1.f, 0.f, 1.f, 0.f);
        sA[j][0]=s.x; sA[j][1]=s.y; sA[j][2]=s.z; sA[j][3]=s.w;
        pre_compose(gAa, gBa, s.x, s.y);
        pre_compose(gAr, gBr, s.z, s.w);
    }
    #pragma unroll
    for (int st = 1; st < 64; st <<= 1) {
        float oAa = __shfl_down(gAa, st);
        float oBa = __shfl_down(gBa, st);
        float oAr = __shfl_down(gAr, st);
        float oBr = __shfl_down(gBr, st);
        if (lane + st < 64) {
            post_compose(gAa, gBa, oAa, oBa);
            post_compose(gAr, gBr, oAr, oBr);
        }
    }
    // within-wave exclusive
    float e2Aa = __shfl_down(gAa, 1);
    float e2Ba = __shfl_down(gBa, 1);
    float e2Ar = __shfl_down(gAr, 1);
    float e2Br = __shfl_down(gBr, 1);
    if (lane == 63) { e2Aa=1.f; e2Ba=0.f; e2Ar=1.f; e2Br=0.f; }

    if (lane == 0) { wSum[w][0]=gAa; wSum[w][1]=gBa; wSum[w][2]=gAr; wSum[w][3]=gBr; }
    if (tid == 0)  { s_cb[0]=0.f; s_cb[1]=0.f; }
    __syncthreads();

    // wave-exclusive over waves w+1..3
    float XAa=1.f, XBa=0.f, XAr=1.f, XBr=0.f;
    for (int j = 3; j > w; --j) {
        pre_compose(XAa, XBa, wSum[j][0], wSum[j][1]);
        pre_compose(XAr, XBr, wSum[j][2], wSum[j][3]);
    }
    // E_t = e2 ∘ X  (map of summaries t*4+4 .. end)
    post_compose(e2Aa, e2Ba, XAa, XBa);
    post_compose(e2Ar, e2Br, XAr, XBr);

    // value at position 4t+4 applied to 0 is the B component; fold down to 4t
    float valA = e2Ba, valR = e2Br;
    #pragma unroll
    for (int j = 3; j >= 0; --j) {
        valA = fmaf(sA[j][0], valA, sA[j][1]);
        valR = fmaf(sA[j][2], valR, sA[j][3]);
        if (4 * tid + j == p) { s_cb[0] = valA; s_cb[1] = valR; }
    }
    __syncthreads();
    const float cbA = s_cb[0];
    const float cbR = s_cb[1];

    // ---------------- Phase C: replay + store ----------------
    float xa = fmaf(WAa, cbA, WBa);   // value at this wave's right edge
    float xr = fmaf(WAr, cbR, WBr);
    xa = fmaf(eAa, xa, eBa);          // value at this thread's right edge
    xr = fmaf(eAr, xr, eBr);

    float ra[SEQ], rt[SEQ];
    #pragma unroll
    for (int i = SEQ - 1; i >= 0; --i) {
        bool val = (vbits >> i) & 1u;
        float a = val ? GAMMA * TAU * fm[i] : 1.f;
        float c = val ? GAMMA * fm[i]       : 1.f;
        xa = fmaf(a, xa, delta[i]);
        xr = fmaf(c, xr, dd[i]);
        ra[i] = xa; rt[i] = xr;
    }

    if (full) {
        #pragma unroll
        for (int q = 0; q < SEQ / 4; ++q) {
            ((float4*)(out_adv + base))[q] =
                make_float4(ra[4*q], ra[4*q+1], ra[4*q+2], ra[4*q+3]);
            ((float4*)(out_ret + base))[q] =
                make_float4(rt[4*q], rt[4*q+1], rt[4*q+2], rt[4*q+3]);
        }
    } else {
        #pragma unroll
        for (int i = 0; i < SEQ; ++i) {
            if (base + i < (long)T) {
                out_adv[base + i] = ra[i];
                out_ret[base + i] = rt[i];
            }
        }
    }
}

// =====================================================================
// Fallback 3-kernel path (verified in round 1) — used if cooperative
// launch can't fit all blocks co-resident.
// =====================================================================
__global__ __launch_bounds__(BLK) void k_summary(
    const float* __restrict__ r, const float* __restrict__ v,
    const float* __restrict__ nv, const int* __restrict__ m,
    float4* __restrict__ blk_sum, int T)
{
    const int  tid  = threadIdx.x;
    const int  lane = tid & 63;
    const int  w    = tid >> 6;
    const long base = (long)blockIdx.x * CHUNK + (long)tid * SEQ;

    float Aa = 1.f, Ba = 0.f, Ar = 1.f, Br = 0.f;

    if (base + SEQ <= (long)T) {
        float rr[SEQ], vv[SEQ + 1], nn[SEQ], fm[SEQ];
        #pragma unroll
        for (int q = 0; q < SEQ / 4; ++q) {
            float4 t0 = ((const float4*)(r  + base))[q];
            rr[4*q+0]=t0.x; rr[4*q+1]=t0.y; rr[4*q+2]=t0.z; rr[4*q+3]=t0.w;
            float4 t1 = ((const float4*)(v  + base))[q];
            vv[4*q+0]=t1.x; vv[4*q+1]=t1.y; vv[4*q+2]=t1.z; vv[4*q+3]=t1.w;
            float4 t2 = ((const float4*)(nv + base))[q];
            nn[4*q+0]=t2.x; nn[4*q+1]=t2.y; nn[4*q+2]=t2.z; nn[4*q+3]=t2.w;
            int4   t3 = ((const int4*)(m   + base))[q];
            fm[4*q+0]=(float)t3.x; fm[4*q+1]=(float)t3.y;
            fm[4*q+2]=(float)t3.z; fm[4*q+3]=(float)t3.w;
        }
        vv[SEQ] = (base + SEQ < (long)T) ? v[base + SEQ] : 0.f;
        #pragma unroll
        for (int i = SEQ - 1; i >= 0; --i) {
            float a = GAMMA * TAU * fm[i];
            float b = rr[i] + GAMMA * fm[i] * vv[i+1] - vv[i];
            float c = GAMMA * fm[i];
            float d = rr[i] + GAMMA * (1.f - fm[i]) * nn[i];
            pre_compose(Aa, Ba, a, b);
            pre_compose(Ar, Br, c, d);
        }
    } else if (base < (long)T) {
        #pragma unroll
        for (int ii = 0; ii < SEQ; ++ii) {
            int i = SEQ - 1 - ii;
            long idx = base + i;
            bool val = idx < (long)T;
            float rr  = val ? r[idx]  : 0.f;
            float vv0 = val ? v[idx]  : 0.f;
            float vv1 = (idx + 1 < (long)T) ? v[idx + 1] : 0.f;
            float nn  = val ? nv[idx] : 0.f;
            float fm  = val ? (float)m[idx] : 0.f;
            float a = val ? GAMMA * TAU * fm : 1.f;
            float b = val ? (rr + GAMMA * fm * vv1 - vv0) : 0.f;
            float c = val ? GAMMA * fm : 1.f;
            float d = val ? (rr + GAMMA * (1.f - fm) * nn) : 0.f;
            pre_compose(Aa, Ba, a, b);
            pre_compose(Ar, Br, c, d);
        }
    }

    #pragma unroll
    for (int st = 1; st < 64; st <<= 1) {
        float oAa = __shfl_down(Aa, st);
        float oBa = __shfl_down(Ba, st);
        float oAr = __shfl_down(Ar, st);
        float oBr = __shfl_down(Br, st);
        if (lane + st < 64) {
            post_compose(Aa, Ba, oAa, oBa);
            post_compose(Ar, Br, oAr, oBr);
        }
    }

    __shared__ float wSum[4][4];
    if (lane == 0) { wSum[w][0]=Aa; wSum[w][1]=Ba; wSum[w][2]=Ar; wSum[w][3]=Br; }
    __syncthreads();
    if (tid == 0) {
        float SAa=1.f, SBa=0.f, SAr=1.f, SBr=0.f;
        for (int j = 3; j >= 0; --j) {
            pre_compose(SAa, SBa, wSum[j][0], wSum[j][1]);
            pre_compose(SAr, SBr, wSum[j][2], wSum[j][3]);
        }
        blk_sum[blockIdx.x] = make_float4(SAa, SBa, SAr, SBr);
    }
}

__global__ __launch_bounds__(1024) void k_scan(
    const float4* __restrict__ blk_sum, float2* __restrict__ carry, int n)
{
    __shared__ float sAa[1024], sBa[1024], sAr[1024], sBr[1024];
    const int t = threadIdx.x;
    float Aa=1.f, Ba=0.f, Ar=1.f, Br=0.f;
    if (t < n) { float4 s = blk_sum[t]; Aa=s.x; Ba=s.y; Ar=s.z; Br=s.w; }
    sAa[t]=Aa; sBa[t]=Ba; sAr[t]=Ar; sBr[t]=Br;
    __syncthreads();
    for (int st = 1; st < 1024; st <<= 1) {
        float oAa=1.f, oBa=0.f, oAr=1.f, oBr=0.f;
        if (t + st < 1024) { oAa=sAa[t+st]; oBa=sBa[t+st]; oAr=sAr[t+st]; oBr=sBr[t+st]; }
        __syncthreads();
        post_compose(Aa, Ba, oAa, oBa);
        post_compose(Ar, Br, oAr, oBr);
        sAa[t]=Aa; sBa[t]=Ba; sAr[t]=Ar; sBr[t]=Br;
        __syncthreads();
    }
    if (t < n) {
        float ca = (t + 1 < n) ? sBa[t+1] : 0.f;
        float cr = (t + 1 < n) ? sBr[t+1] : 0.f;
        carry[t] = make_float2(ca, cr);
    }
}

__global__ __launch_bounds__(BLK) void k_final(
    const float* __restrict__ r, const float* __restrict__ v,
    const float* __restrict__ nv, const int* __restrict__ m,
    const float2* __restrict__ carry,
    float* __restrict__ out_adv, float* __restrict__ out_ret, int T)
{
    const int  tid  = threadIdx.x;
    const int  lane = tid & 63;
    const int  w    = tid >> 6;
    const long base = (long)blockIdx.x * CHUNK + (long)tid * SEQ;

    float delta[SEQ], dd[SEQ], fm[SEQ];
    unsigned vbits = 0;
    float Aa = 1.f, Ba = 0.f, Ar = 1.f, Br = 0.f;
    const bool full = (base + SEQ <= (long)T);

    if (full) {
        vbits = 0xFFFFu;
        float rr[SEQ], vv[SEQ + 1], nn[SEQ];
        #pragma unroll
        for (int q = 0; q < SEQ / 4; ++q) {
            float4 t0 = ((const float4*)(r  + base))[q];
            rr[4*q+0]=t0.x; rr[4*q+1]=t0.y; rr[4*q+2]=t0.z; rr[4*q+3]=t0.w;
            float4 t1 = ((const float4*)(v  + base))[q];
            vv[4*q+0]=t1.x; vv[4*q+1]=t1.y; vv[4*q+2]=t1.z; vv[4*q+3]=t1.w;
            float4 t2 = ((const float4*)(nv + base))[q];
            nn[4*q+0]=t2.x; nn[4*q+1]=t2.y; nn[4*q+2]=t2.z; nn[4*q+3]=t2.w;
            int4   t3 = ((const int4*)(m   + base))[q];
            fm[4*q+0]=(float)t3.x; fm[4*q+1]=(float)t3.y;
            fm[4*q+2]=(float)t3.z; fm[4*q+3]=(float)t3.w;
        }
        vv[SEQ] = (base + SEQ < (long)T) ? v[base + SEQ] : 0.f;
        #pragma unroll
        for (int i = SEQ - 1; i >= 0; --i) {
            delta[i] = rr[i] + GAMMA * fm[i] * vv[i+1] - vv[i];
            dd[i]    = rr[i] + GAMMA * (1.f - fm[i]) * nn[i];
            pre_compose(Aa, Ba, GAMMA * TAU * fm[i], delta[i]);
            pre_compose(Ar, Br, GAMMA * fm[i], dd[i]);
        }
    } else {
        #pragma unroll
        for (int ii = 0; ii < SEQ; ++ii) {
            int i = SEQ - 1 - ii;
            long idx = base + i;
            bool val = idx < (long)T;
            float rr  = val ? r[idx]  : 0.f;
            float vv0 = val ? v[idx]  : 0.f;
            float vv1 = (idx + 1 < (long)T) ? v[idx + 1] : 0.f;
            float nn  = val ? nv[idx] : 0.f;
            fm[i] = val ? (float)m[idx] : 0.f;
            if (val) vbits |= (1u << i);
            delta[i] = val ? (rr + GAMMA * fm[i] * vv1 - vv0) : 0.f;
            dd[i]    = val ? (rr + GAMMA * (1.f - fm[i]) * nn) : 0.f;
            pre_compose(Aa, Ba, val ? GAMMA * TAU * fm[i] : 1.f, delta[i]);
            pre_compose(Ar, Br, val ? GAMMA * fm[i] : 1.f, dd[i]);
        }
    }

    #pragma unroll
    for (int st = 1; st < 64; st <<= 1) {
        float oAa = __shfl_down(Aa, st);
        float oBa = __shfl_down(Ba, st);
        float oAr = __shfl_down(Ar, st);
        float oBr = __shfl_down(Br, st);
        if (lane + st < 64) {
            post_compose(Aa, Ba, oAa, oBa);
            post_compose(Ar, Br, oAr, oBr);
        }
    }
    float eAa = __shfl_down(Aa, 1);
    float eBa = __shfl_down(Ba, 1);
    float eAr = __shfl_down(Ar, 1);
    float eBr = __shfl_down(Br, 1);
    if (lane == 63) { eAa=1.f; eBa=0.f; eAr=1.f; eBr=0.f; }

    __shared__ float wSum[4][4];
    if (lane == 0) { wSum[w][0]=Aa; wSum[w][1]=Ba; wSum[w][2]=Ar; wSum[w][3]=Br; }
    __syncthreads();

    float WAa=1.f, WBa=0.f, WAr=1.f, WBr=0.f;
    for (int j = 3; j > w; --j) {
        pre_compose(WAa, WBa, wSum[j][0], wSum[j][1]);
        pre_compose(WAr, WBr, wSum[j][2], wSum[j][3]);
    }

    float2 cb = carry[blockIdx.x];
    float xa = fmaf(WAa, cb.x, WBa);
    float xr = fmaf(WAr, cb.y, WBr);
    xa = fmaf(eAa, xa, eBa);
    xr = fmaf(eAr, xr, eBr);

    float ra[SEQ], rt[SEQ];
    #pragma unroll
    for (int i = SEQ - 1; i >= 0; --i) {
        bool val = (vbits >> i) & 1u;
        float a = val ? GAMMA * TAU * fm[i] : 1.f;
        float c = val ? GAMMA * fm[i]       : 1.f;
        xa = fmaf(a, xa, delta[i]);
        xr = fmaf(c, xr, dd[i]);
        ra[i] = xa; rt[i] = xr;
    }

    if (full) {
        #pragma unroll
        for (int q = 0; q < SEQ / 4; ++q) {
            ((float4*)(out_adv + base))[q] =
                make_float4(ra[4*q], ra[4*q+1], ra[4*q+2], ra[4*q+3]);
            ((float4*)(out_ret + base))[q] =
                make_float4(rt[4*q], rt[4*q+1], rt[4*q+2], rt[4*q+3]);
        }
    } else {
        #pragma unroll
        for (int i = 0; i < SEQ; ++i) {
            if (base + i < (long)T) {
                out_adv[base + i] = ra[i];
                out_ret[base + i] = rt[i];
            }
        }
    }
}

extern "C" void kernel_launch(void* const* d_in, const int* in_sizes, int n_in,
                              void* d_out, int out_size, void* d_ws, size_t ws_size,
                              hipStream_t stream) {
    const float* r  = (const float*)d_in[0];
    const float* v  = (const float*)d_in[1];
    const float* nv = (const float*)d_in[2];
    const int*   m  = (const int*)d_in[3];
    const int T = in_sizes[0];
    const int nblk = (T + CHUNK - 1) / CHUNK;   // 1024 for T = 4'194'304

    float4* blk_sum = (float4*)d_ws;
    float2* carry   = (float2*)((char*)d_ws + (size_t)nblk * sizeof(float4));

    float* out_adv = (float*)d_out;
    float* out_ret = (float*)d_out + T;

    // --- try fused cooperative path (needs all blocks co-resident, nblk<=1024) ---
    bool coop_ok = false;
    if (nblk <= 1024) {
        int maxPerCU = 0;
        if (hipOccupancyMaxActiveBlocksPerMultiprocessor(
                &maxPerCU, (const void*)k_fused, BLK, 0) == hipSuccess) {
            int dev = 0;
            hipGetDevice(&dev);
            hipDeviceProp_t prop;
            if (hipGetDeviceProperties(&prop, dev) == hipSuccess) {
                coop_ok = ((long)maxPerCU * (long)prop.multiProcessorCount >= (long)nblk);
            }
        }
    }

    if (coop_ok) {
        int Targ = T;
        void* args[] = { (void*)&r, (void*)&v, (void*)&nv, (void*)&m,
                         (void*)&blk_sum, (void*)&out_adv, (void*)&out_ret,
                         (void*)&Targ };
        hipError_t e = hipLaunchCooperativeKernel((const void*)k_fused,
                                                  dim3(nblk), dim3(BLK),
                                                  args, 0, stream);
        if (e == hipSuccess) return;
    }

    // --- fallback: verified 3-kernel path ---
    k_summary<<<nblk, BLK, 0, stream>>>(r, v, nv, m, blk_sum, T);
    k_scan<<<1, 1024, 0, stream>>>(blk_sum, carry, nblk);
    k_final<<<nblk, BLK, 0, stream>>>(r, v, nv, m, carry, out_adv, out_ret, T);
}

// Round 3
// 39.886 us; speedup vs baseline: 1.1052x; 1.1052x over previous
//
#include <hip/hip_runtime.h>

#define GAMMA 0.99f
#define TAU   0.95f

constexpr int SEQ   = 16;          // elements per thread
constexpr int BLK   = 256;         // threads per block
constexpr int CHUNK = BLK * SEQ;   // 4096 elements per block

// (A,B) = (A,B) ∘ (rA,rB)  — apply right operand first, then (A,B)
__device__ __forceinline__ void post_compose(float& A, float& B, float rA, float rB) {
    B = fmaf(A, rB, B);
    A *= rA;
}
// (A,B) = (lA,lB) ∘ (A,B)  — apply (A,B) first, then left operand
__device__ __forceinline__ void pre_compose(float& A, float& B, float lA, float lB) {
    B = fmaf(lA, B, lB);
    A *= lA;
}

// ---------------- Kernel 1: per-block affine summaries ----------------
__global__ __launch_bounds__(BLK) void k_summary(
    const float* __restrict__ r, const float* __restrict__ v,
    const float* __restrict__ nv, const int* __restrict__ m,
    float4* __restrict__ blk_sum, int T)
{
    const int  tid  = threadIdx.x;
    const int  lane = tid & 63;
    const int  w    = tid >> 6;
    const long base = (long)blockIdx.x * CHUNK + (long)tid * SEQ;

    float Aa = 1.f, Ba = 0.f, Ar = 1.f, Br = 0.f;

    if (base + SEQ <= (long)T) {
        float rr[SEQ], vv[SEQ + 1], nn[SEQ], fm[SEQ];
        #pragma unroll
        for (int q = 0; q < SEQ / 4; ++q) {
            float4 t0 = ((const float4*)(r  + base))[q];
            rr[4*q+0]=t0.x; rr[4*q+1]=t0.y; rr[4*q+2]=t0.z; rr[4*q+3]=t0.w;
            float4 t1 = ((const float4*)(v  + base))[q];
            vv[4*q+0]=t1.x; vv[4*q+1]=t1.y; vv[4*q+2]=t1.z; vv[4*q+3]=t1.w;
            float4 t2 = ((const float4*)(nv + base))[q];
            nn[4*q+0]=t2.x; nn[4*q+1]=t2.y; nn[4*q+2]=t2.z; nn[4*q+3]=t2.w;
            int4   t3 = ((const int4*)(m   + base))[q];
            fm[4*q+0]=(float)t3.x; fm[4*q+1]=(float)t3.y;
            fm[4*q+2]=(float)t3.z; fm[4*q+3]=(float)t3.w;
        }
        vv[SEQ] = (base + SEQ < (long)T) ? v[base + SEQ] : 0.f;
        #pragma unroll
        for (int i = SEQ - 1; i >= 0; --i) {
            float a = GAMMA * TAU * fm[i];
            float b = rr[i] + GAMMA * fm[i] * vv[i+1] - vv[i];
            float c = GAMMA * fm[i];
            float d = rr[i] + GAMMA * (1.f - fm[i]) * nn[i];
            pre_compose(Aa, Ba, a, b);
            pre_compose(Ar, Br, c, d);
        }
    } else if (base < (long)T) {
        #pragma unroll
        for (int ii = 0; ii < SEQ; ++ii) {
            int i = SEQ - 1 - ii;
            long idx = base + i;
            bool val = idx < (long)T;
            float rr  = val ? r[idx]  : 0.f;
            float vv0 = val ? v[idx]  : 0.f;
            float vv1 = (idx + 1 < (long)T) ? v[idx + 1] : 0.f;
            float nn  = val ? nv[idx] : 0.f;
            float fm  = val ? (float)m[idx] : 0.f;
            float a = val ? GAMMA * TAU * fm : 1.f;
            float b = val ? (rr + GAMMA * fm * vv1 - vv0) : 0.f;
            float c = val ? GAMMA * fm : 1.f;
            float d = val ? (rr + GAMMA * (1.f - fm) * nn) : 0.f;
            pre_compose(Aa, Ba, a, b);
            pre_compose(Ar, Br, c, d);
        }
    }

    // wave-level suffix scan (contiguous segments -> OK for non-commutative op)
    #pragma unroll
    for (int st = 1; st < 64; st <<= 1) {
        float oAa = __shfl_down(Aa, st);
        float oBa = __shfl_down(Ba, st);
        float oAr = __shfl_down(Ar, st);
        float oBr = __shfl_down(Br, st);
        if (lane + st < 64) {
            post_compose(Aa, Ba, oAa, oBa);
            post_compose(Ar, Br, oAr, oBr);
        }
    }

    __shared__ float wSum[4][4];
    if (lane == 0) { wSum[w][0]=Aa; wSum[w][1]=Ba; wSum[w][2]=Ar; wSum[w][3]=Br; }
    __syncthreads();
    if (tid == 0) {
        float SAa=1.f, SBa=0.f, SAr=1.f, SBr=0.f;
        for (int j = 3; j >= 0; --j) {
            pre_compose(SAa, SBa, wSum[j][0], wSum[j][1]);
            pre_compose(SAr, SBr, wSum[j][2], wSum[j][3]);
        }
        blk_sum[blockIdx.x] = make_float4(SAa, SBa, SAr, SBr);
    }
}

// ---------------- Kernel 2: redundant summary-scan + replay + store ----------------
// Each block re-derives its own carry by suffix-scanning all <=1024 block
// summaries (16KB, L2/L3-resident). Requires nblk <= 4*BLK.
__global__ __launch_bounds__(BLK) void k_final2(
    const float* __restrict__ r, const float* __restrict__ v,
    const float* __restrict__ nv, const int* __restrict__ m,
    const float4* __restrict__ blk_sum,
    float* __restrict__ out_adv, float* __restrict__ out_ret, int T, int nblk)
{
    const int  tid  = threadIdx.x;
    const int  lane = tid & 63;
    const int  w    = tid >> 6;
    const int  b    = blockIdx.x;
    const long base = (long)b * CHUNK + (long)tid * SEQ;

    __shared__ float wSum[4][4];
    __shared__ float s_cb[2];

    // ---- Phase B: carry for this block from summaries ----
    {
        const int p = b + 1;               // position whose value is our carry
        float sA[4][4];
        float gAa=1.f, gBa=0.f, gAr=1.f, gBr=0.f;
        #pragma unroll
        for (int j = 3; j >= 0; --j) {
            int idx = 4 * tid + j;
            float4 s = (idx < nblk) ? blk_sum[idx] : make_float4(1.f, 0.f, 1.f, 0.f);
            sA[j][0]=s.x; sA[j][1]=s.y; sA[j][2]=s.z; sA[j][3]=s.w;
            pre_compose(gAa, gBa, s.x, s.y);
            pre_compose(gAr, gBr, s.z, s.w);
        }
        #pragma unroll
        for (int st = 1; st < 64; st <<= 1) {
            float oAa = __shfl_down(gAa, st);
            float oBa = __shfl_down(gBa, st);
            float oAr = __shfl_down(gAr, st);
            float oBr = __shfl_down(gBr, st);
            if (lane + st < 64) {
                post_compose(gAa, gBa, oAa, oBa);
                post_compose(gAr, gBr, oAr, oBr);
            }
        }
        // within-wave exclusive (lanes lane+1..63)
        float e2Aa = __shfl_down(gAa, 1);
        float e2Ba = __shfl_down(gBa, 1);
        float e2Ar = __shfl_down(gAr, 1);
        float e2Br = __shfl_down(gBr, 1);
        if (lane == 63) { e2Aa=1.f; e2Ba=0.f; e2Ar=1.f; e2Br=0.f; }

        if (lane == 0) { wSum[w][0]=gAa; wSum[w][1]=gBa; wSum[w][2]=gAr; wSum[w][3]=gBr; }
        if (tid == 0)  { s_cb[0]=0.f; s_cb[1]=0.f; }
        __syncthreads();

        // wave-exclusive map over waves w+1..3
        float XAa=1.f, XBa=0.f, XAr=1.f, XBr=0.f;
        for (int j = 3; j > w; --j) {
            pre_compose(XAa, XBa, wSum[j][0], wSum[j][1]);
            pre_compose(XAr, XBr, wSum[j][2], wSum[j][3]);
        }
        // E_t = e2 ∘ X  (map of summaries 4t+4 .. end); value at 4t+4 = B comp
        post_compose(e2Aa, e2Ba, XAa, XBa);
        post_compose(e2Ar, e2Br, XAr, XBr);

        float valA = e2Ba, valR = e2Br;
        #pragma unroll
        for (int j = 3; j >= 0; --j) {
            valA = fmaf(sA[j][0], valA, sA[j][1]);
            valR = fmaf(sA[j][2], valR, sA[j][3]);
            if (4 * tid + j == p) { s_cb[0] = valA; s_cb[1] = valR; }
        }
        __syncthreads();   // s_cb ready; wSum free for reuse below
    }
    const float cbA = s_cb[0];
    const float cbR = s_cb[1];

    // ---- Phase A: load chunk + per-element maps ----
    float delta[SEQ], dd[SEQ], fm[SEQ];
    unsigned vbits = 0;
    float Aa = 1.f, Ba = 0.f, Ar = 1.f, Br = 0.f;
    const bool full = (base + SEQ <= (long)T);

    if (full) {
        vbits = 0xFFFFu;
        float rr[SEQ], vv[SEQ + 1], nn[SEQ];
        #pragma unroll
        for (int q = 0; q < SEQ / 4; ++q) {
            float4 t0 = ((const float4*)(r  + base))[q];
            rr[4*q+0]=t0.x; rr[4*q+1]=t0.y; rr[4*q+2]=t0.z; rr[4*q+3]=t0.w;
            float4 t1 = ((const float4*)(v  + base))[q];
            vv[4*q+0]=t1.x; vv[4*q+1]=t1.y; vv[4*q+2]=t1.z; vv[4*q+3]=t1.w;
            float4 t2 = ((const float4*)(nv + base))[q];
            nn[4*q+0]=t2.x; nn[4*q+1]=t2.y; nn[4*q+2]=t2.z; nn[4*q+3]=t2.w;
            int4   t3 = ((const int4*)(m   + base))[q];
            fm[4*q+0]=(float)t3.x; fm[4*q+1]=(float)t3.y;
            fm[4*q+2]=(float)t3.z; fm[4*q+3]=(float)t3.w;
        }
        vv[SEQ] = (base + SEQ < (long)T) ? v[base + SEQ] : 0.f;
        #pragma unroll
        for (int i = SEQ - 1; i >= 0; --i) {
            delta[i] = rr[i] + GAMMA * fm[i] * vv[i+1] - vv[i];
            dd[i]    = rr[i] + GAMMA * (1.f - fm[i]) * nn[i];
            pre_compose(Aa, Ba, GAMMA * TAU * fm[i], delta[i]);
            pre_compose(Ar, Br, GAMMA * fm[i], dd[i]);
        }
    } else {
        #pragma unroll
        for (int ii = 0; ii < SEQ; ++ii) {
            int i = SEQ - 1 - ii;
            long idx = base + i;
            bool val = idx < (long)T;
            float rr  = val ? r[idx]  : 0.f;
            float vv0 = val ? v[idx]  : 0.f;
            float vv1 = (idx + 1 < (long)T) ? v[idx + 1] : 0.f;
            float nn  = val ? nv[idx] : 0.f;
            fm[i] = val ? (float)m[idx] : 0.f;
            if (val) vbits |= (1u << i);
            delta[i] = val ? (rr + GAMMA * fm[i] * vv1 - vv0) : 0.f;
            dd[i]    = val ? (rr + GAMMA * (1.f - fm[i]) * nn) : 0.f;
            pre_compose(Aa, Ba, val ? GAMMA * TAU * fm[i] : 1.f, delta[i]);
            pre_compose(Ar, Br, val ? GAMMA * fm[i] : 1.f, dd[i]);
        }
    }

    // wave-level inclusive suffix scan
    #pragma unroll
    for (int st = 1; st < 64; st <<= 1) {
        float oAa = __shfl_down(Aa, st);
        float oBa = __shfl_down(Ba, st);
        float oAr = __shfl_down(Ar, st);
        float oBr = __shfl_down(Br, st);
        if (lane + st < 64) {
            post_compose(Aa, Ba, oAa, oBa);
            post_compose(Ar, Br, oAr, oBr);
        }
    }
    // thread-exclusive (within wave)
    float eAa = __shfl_down(Aa, 1);
    float eBa = __shfl_down(Ba, 1);
    float eAr = __shfl_down(Ar, 1);
    float eBr = __shfl_down(Br, 1);
    if (lane == 63) { eAa=1.f; eBa=0.f; eAr=1.f; eBr=0.f; }

    if (lane == 0) { wSum[w][0]=Aa; wSum[w][1]=Ba; wSum[w][2]=Ar; wSum[w][3]=Br; }
    __syncthreads();

    // wave-exclusive map: waves w+1..3
    float WAa=1.f, WBa=0.f, WAr=1.f, WBr=0.f;
    for (int j = 3; j > w; --j) {
        pre_compose(WAa, WBa, wSum[j][0], wSum[j][1]);
        pre_compose(WAr, WBr, wSum[j][2], wSum[j][3]);
    }

    // ---- Phase C: replay + store ----
    float xa = fmaf(WAa, cbA, WBa);   // value at this wave's right edge
    float xr = fmaf(WAr, cbR, WBr);
    xa = fmaf(eAa, xa, eBa);          // value at this thread's right edge
    xr = fmaf(eAr, xr, eBr);

    float ra[SEQ], rt[SEQ];
    #pragma unroll
    for (int i = SEQ - 1; i >= 0; --i) {
        bool val = (vbits >> i) & 1u;
        float a = val ? GAMMA * TAU * fm[i] : 1.f;
        float c = val ? GAMMA * fm[i]       : 1.f;
        xa = fmaf(a, xa, delta[i]);
        xr = fmaf(c, xr, dd[i]);
        ra[i] = xa; rt[i] = xr;
    }

    if (full) {
        #pragma unroll
        for (int q = 0; q < SEQ / 4; ++q) {
            ((float4*)(out_adv + base))[q] =
                make_float4(ra[4*q], ra[4*q+1], ra[4*q+2], ra[4*q+3]);
            ((float4*)(out_ret + base))[q] =
                make_float4(rt[4*q], rt[4*q+1], rt[4*q+2], rt[4*q+3]);
        }
    } else {
        #pragma unroll
        for (int i = 0; i < SEQ; ++i) {
            if (base + i < (long)T) {
                out_adv[base + i] = ra[i];
                out_ret[base + i] = rt[i];
            }
        }
    }
}

// ---------------- Fallback middle kernel (only if nblk > 4*BLK) ----------------
__global__ __launch_bounds__(1024) void k_scan(
    const float4* __restrict__ blk_sum, float2* __restrict__ carry, int n)
{
    __shared__ float sAa[1024], sBa[1024], sAr[1024], sBr[1024];
    const int t = threadIdx.x;
    float Aa=1.f, Ba=0.f, Ar=1.f, Br=0.f;
    if (t < n) { float4 s = blk_sum[t]; Aa=s.x; Ba=s.y; Ar=s.z; Br=s.w; }
    sAa[t]=Aa; sBa[t]=Ba; sAr[t]=Ar; sBr[t]=Br;
    __syncthreads();
    for (int st = 1; st < 1024; st <<= 1) {
        float oAa=1.f, oBa=0.f, oAr=1.f, oBr=0.f;
        if (t + st < 1024) { oAa=sAa[t+st]; oBa=sBa[t+st]; oAr=sAr[t+st]; oBr=sBr[t+st]; }
        __syncthreads();
        post_compose(Aa, Ba, oAa, oBa);
        post_compose(Ar, Br, oAr, oBr);
        sAa[t]=Aa; sBa[t]=Ba; sAr[t]=Ar; sBr[t]=Br;
        __syncthreads();
    }
    if (t < n) {
        float ca = (t + 1 < n) ? sBa[t+1] : 0.f;
        float cr = (t + 1 < n) ? sBr[t+1] : 0.f;
        carry[t] = make_float2(ca, cr);
    }
}

__global__ __launch_bounds__(BLK) void k_final(
    const float* __restrict__ r, const float* __restrict__ v,
    const float* __restrict__ nv, const int* __restrict__ m,
    const float2* __restrict__ carry,
    float* __restrict__ out_adv, float* __restrict__ out_ret, int T)
{
    const int  tid  = threadIdx.x;
    const int  lane = tid & 63;
    const int  w    = tid >> 6;
    const long base = (long)blockIdx.x * CHUNK + (long)tid * SEQ;

    float delta[SEQ], dd[SEQ], fm[SEQ];
    unsigned vbits = 0;
    float Aa = 1.f, Ba = 0.f, Ar = 1.f, Br = 0.f;
    const bool full = (base + SEQ <= (long)T);

    if (full) {
        vbits = 0xFFFFu;
        float rr[SEQ], vv[SEQ + 1], nn[SEQ];
        #pragma unroll
        for (int q = 0; q < SEQ / 4; ++q) {
            float4 t0 = ((const float4*)(r  + base))[q];
            rr[4*q+0]=t0.x; rr[4*q+1]=t0.y; rr[4*q+2]=t0.z; rr[4*q+3]=t0.w;
            float4 t1 = ((const float4*)(v  + base))[q];
            vv[4*q+0]=t1.x; vv[4*q+1]=t1.y; vv[4*q+2]=t1.z; vv[4*q+3]=t1.w;
            float4 t2 = ((const float4*)(nv + base))[q];
            nn[4*q+0]=t2.x; nn[4*q+1]=t2.y; nn[4*q+2]=t2.z; nn[4*q+3]=t2.w;
            int4   t3 = ((const int4*)(m   + base))[q];
            fm[4*q+0]=(float)t3.x; fm[4*q+1]=(float)t3.y;
            fm[4*q+2]=(float)t3.z; fm[4*q+3]=(float)t3.w;
        }
        vv[SEQ] = (base + SEQ < (long)T) ? v[base + SEQ] : 0.f;
        #pragma unroll
        for (int i = SEQ - 1; i >= 0; --i) {
            delta[i] = rr[i] + GAMMA * fm[i] * vv[i+1] - vv[i];
            dd[i]    = rr[i] + GAMMA * (1.f - fm[i]) * nn[i];
            pre_compose(Aa, Ba, GAMMA * TAU * fm[i], delta[i]);
            pre_compose(Ar, Br, GAMMA * fm[i], dd[i]);
        }
    } else {
        #pragma unroll
        for (int ii = 0; ii < SEQ; ++ii) {
            int i = SEQ - 1 - ii;
            long idx = base + i;
            bool val = idx < (long)T;
            float rr  = val ? r[idx]  : 0.f;
            float vv0 = val ? v[idx]  : 0.f;
            float vv1 = (idx + 1 < (long)T) ? v[idx + 1] : 0.f;
            float nn  = val ? nv[idx] : 0.f;
            fm[i] = val ? (float)m[idx] : 0.f;
            if (val) vbits |= (1u << i);
            delta[i] = val ? (rr + GAMMA * fm[i] * vv1 - vv0) : 0.f;
            dd[i]    = val ? (rr + GAMMA * (1.f - fm[i]) * nn) : 0.f;
            pre_compose(Aa, Ba, val ? GAMMA * TAU * fm[i] : 1.f, delta[i]);
            pre_compose(Ar, Br, val ? GAMMA * fm[i] : 1.f, dd[i]);
        }
    }

    #pragma unroll
    for (int st = 1; st < 64; st <<= 1) {
        float oAa = __shfl_down(Aa, st);
        float oBa = __shfl_down(Ba, st);
        float oAr = __shfl_down(Ar, st);
        float oBr = __shfl_down(Br, st);
        if (lane + st < 64) {
            post_compose(Aa, Ba, oAa, oBa);
            post_compose(Ar, Br, oAr, oBr);
        }
    }
    float eAa = __shfl_down(Aa, 1);
    float eBa = __shfl_down(Ba, 1);
    float eAr = __shfl_down(Ar, 1);
    float eBr = __shfl_down(Br, 1);
    if (lane == 63) { eAa=1.f; eBa=0.f; eAr=1.f; eBr=0.f; }

    __shared__ float wSum[4][4];
    if (lane == 0) { wSum[w][0]=Aa; wSum[w][1]=Ba; wSum[w][2]=Ar; wSum[w][3]=Br; }
    __syncthreads();

    float WAa=1.f, WBa=0.f, WAr=1.f, WBr=0.f;
    for (int j = 3; j > w; --j) {
        pre_compose(WAa, WBa, wSum[j][0], wSum[j][1]);
        pre_compose(WAr, WBr, wSum[j][2], wSum[j][3]);
    }

    float2 cb = carry[blockIdx.x];
    float xa = fmaf(WAa, cb.x, WBa);
    float xr = fmaf(WAr, cb.y, WBr);
    xa = fmaf(eAa, xa, eBa);
    xr = fmaf(eAr, xr, eBr);

    float ra[SEQ], rt[SEQ];
    #pragma unroll
    for (int i = SEQ - 1; i >= 0; --i) {
        bool val = (vbits >> i) & 1u;
        float a = val ? GAMMA * TAU * fm[i] : 1.f;
        float c = val ? GAMMA * fm[i]       : 1.f;
        xa = fmaf(a, xa, delta[i]);
        xr = fmaf(c, xr, dd[i]);
        ra[i] = xa; rt[i] = xr;
    }

    if (full) {
        #pragma unroll
        for (int q = 0; q < SEQ / 4; ++q) {
            ((float4*)(out_adv + base))[q] =
                make_float4(ra[4*q], ra[4*q+1], ra[4*q+2], ra[4*q+3]);
            ((float4*)(out_ret + base))[q] =
                make_float4(rt[4*q], rt[4*q+1], rt[4*q+2], rt[4*q+3]);
        }
    } else {
        #pragma unroll
        for (int i = 0; i < SEQ; ++i) {
            if (base + i < (long)T) {
                out_adv[base + i] = ra[i];
                out_ret[base + i] = rt[i];
            }
        }
    }
}

extern "C" void kernel_launch(void* const* d_in, const int* in_sizes, int n_in,
                              void* d_out, int out_size, void* d_ws, size_t ws_size,
                              hipStream_t stream) {
    const float* r  = (const float*)d_in[0];
    const float* v  = (const float*)d_in[1];
    const float* nv = (const float*)d_in[2];
    const int*   m  = (const int*)d_in[3];
    const int T = in_sizes[0];
    const int nblk = (T + CHUNK - 1) / CHUNK;   // 1024 for T = 4'194'304

    float4* blk_sum = (float4*)d_ws;
    float2* carry   = (float2*)((char*)d_ws + (size_t)nblk * sizeof(float4));

    float* out_adv = (float*)d_out;
    float* out_ret = (float*)d_out + T;

    if (nblk <= 4 * BLK) {
        // 2-kernel path: every block re-derives its carry from the summaries
        k_summary<<<nblk, BLK, 0, stream>>>(r, v, nv, m, blk_sum, T);
        k_final2<<<nblk, BLK, 0, stream>>>(r, v, nv, m, blk_sum,
                                           out_adv, out_ret, T, nblk);
    } else {
        // generic 3-kernel path
        k_summary<<<nblk, BLK, 0, stream>>>(r, v, nv, m, blk_sum, T);
        k_scan<<<1, 1024, 0, stream>>>(blk_sum, carry, nblk);
        k_final<<<nblk, BLK, 0, stream>>>(r, v, nv, m, carry, out_adv, out_ret, T);
    }
}